// Round 15
// baseline (2762.594 us; speedup 1.0000x reference)
//
#include <hip/hip_runtime.h>
#include <hip/hip_bf16.h>

#define NN 100000
#define NEDGE 1600000
#define NV (NN*32)
#define NEG 0.01f
#define EPS 1e-5f
#define NBLK 391            // ceil(NN/256)

// ---- static device arena (fp32) ----
#define OFF_STATS 0
#define OFF_PA   2048
#define OFF_PB   (OFF_PA + NV)
#define OFF_AGG  (OFF_PB + NV)
#define OFF_MSGB (OFF_AGG + NV)          // NV bf16 = NV/2 floats
#define OFF_RING (OFF_MSGB + NV/2)
#define ARENA_F  (OFF_RING + 4*NV)

__device__ __align__(16) float gA[ARENA_F];
__device__ int g_cnt[NN];
__device__ int g_rowptr[NN + 1];
__device__ int g_cur[NN];
__device__ int g_csr[NEDGE];
__device__ int g_bsum[NBLK];
__device__ int g_boff[NBLK];

__device__ __forceinline__ float lrelu(float v) { return v > 0.f ? v : v * NEG; }
__device__ __forceinline__ unsigned short f2b(float v) {
    __hip_bfloat16 b = __float2bfloat16(v);
    return *reinterpret_cast<unsigned short*>(&b);
}
__device__ __forceinline__ float b2f(unsigned short u) {
    __hip_bfloat16 b = *reinterpret_cast<__hip_bfloat16*>(&u);
    return __bfloat162float(b);
}

// ---------------- zero stats + counts ----------------
__global__ void k_zero_v15()
{
    int i = blockIdx.x * 256 + threadIdx.x;
    if (i < 2048) gA[i] = 0.f;
    if (i < NN) g_cnt[i] = 0;
}

// ---------------- CSR build ----------------
__global__ void k_count_v15(const int* __restrict__ col)
{
    int e = blockIdx.x * 256 + threadIdx.x;
    if (e < NEDGE) atomicAdd(&g_cnt[col[NEDGE + e]], 1);
}

__global__ __launch_bounds__(256) void k_bsum_v15()
{
    __shared__ int s[256];
    int i = blockIdx.x * 256 + threadIdx.x;
    int v = (i < NN) ? g_cnt[i] : 0;
    s[threadIdx.x] = v;
    __syncthreads();
    for (int off = 128; off > 0; off >>= 1) {
        if (threadIdx.x < off) s[threadIdx.x] += s[threadIdx.x + off];
        __syncthreads();
    }
    if (threadIdx.x == 0) g_bsum[blockIdx.x] = s[0];
}

__global__ __launch_bounds__(512) void k_bscan_v15()
{
    __shared__ int s[512];
    int t = threadIdx.x;
    int v = (t < NBLK) ? g_bsum[t] : 0;
    s[t] = v;
    __syncthreads();
    for (int off = 1; off < 512; off <<= 1) {
        int u = (t >= off) ? s[t - off] : 0;
        __syncthreads();
        s[t] += u;
        __syncthreads();
    }
    if (t < NBLK) g_boff[t] = s[t] - v;
    if (t == NBLK - 1) g_rowptr[NN] = s[t];
}

__global__ __launch_bounds__(256) void k_bexp_v15()
{
    __shared__ int s[256];
    int i = blockIdx.x * 256 + threadIdx.x;
    int t = threadIdx.x;
    int v = (i < NN) ? g_cnt[i] : 0;
    s[t] = v;
    __syncthreads();
    for (int off = 1; off < 256; off <<= 1) {
        int u = (t >= off) ? s[t - off] : 0;
        __syncthreads();
        s[t] += u;
        __syncthreads();
    }
    if (i < NN) {
        int p = g_boff[blockIdx.x] + s[t] - v;
        g_rowptr[i] = p;
        g_cur[i] = p;
    }
}

__global__ void k_fill_v15(const int* __restrict__ col)
{
    int e = blockIdx.x * 256 + threadIdx.x;
    if (e >= NEDGE) return;
    int s = col[e];
    int d = col[NEDGE + e];
    int pos = atomicAdd(&g_cur[d], 1);
    g_csr[pos] = s;
}

// ---------------- init layer 0: PA = x*Wi0 + bi0, stats -> slot 0 ----------------
__global__ void k_init0_v15(const float* __restrict__ x, const float* __restrict__ Wi0,
                            const float* __restrict__ bi0)
{
    int j = threadIdx.x & 31, ns = threadIdx.x >> 5;
    float w = Wi0[j];
    float bb = bi0[j];
    __shared__ float red[64];
    if (threadIdx.x < 64) red[threadIdx.x] = 0.f;
    __syncthreads();
    float s1 = 0.f, s2 = 0.f;
    for (int t = blockIdx.x; t < NN / 8; t += gridDim.x) {
        int n = t * 8 + ns;
        float v = x[n] * w + bb;
        gA[OFF_PA + n * 32 + j] = v;
        s1 += v; s2 += v * v;
    }
    atomicAdd(&red[j], s1);
    atomicAdd(&red[j + 32], s2);
    __syncthreads();
    if (threadIdx.x < 64) atomicAdd(&gA[OFF_STATS + threadIdx.x], red[threadIdx.x]);
}

// ------- BN+LReLU (+resid) (+feats store) (+fused next 32x32 linear + stats) -------
__global__ void k_nl_v15(int off_in, int off_out, int st_in,
                         const float* __restrict__ gamma, const float* __restrict__ beta,
                         int off_resid, int off_feats,
                         const float* __restrict__ Wn, const float* __restrict__ bn,
                         int st_out)
{
    int j = threadIdx.x & 31, ns = threadIdx.x >> 5;
    float mean = gA[st_in + j] * (1.f / NN);
    float var  = gA[st_in + 32 + j] * (1.f / NN) - mean * mean;
    float scale = gamma[j] * rsqrtf(var + EPS);
    float shift = beta[j] - mean * scale;

    float wc[32]; float bb = 0.f;
    if (Wn) {
        #pragma unroll
        for (int k = 0; k < 32; ++k) wc[k] = Wn[k * 32 + j];
        bb = bn[j];
    }
    __shared__ float sH[8][32];
    __shared__ float red[64];
    if (threadIdx.x < 64) red[threadIdx.x] = 0.f;
    __syncthreads();
    float s1 = 0.f, s2 = 0.f;
    for (int t = blockIdx.x; t < NN / 8; t += gridDim.x) {
        int n = t * 8 + ns;
        float v = gA[off_in + n * 32 + j];
        v = lrelu(scale * v + shift);
        if (off_resid >= 0) v += gA[off_resid + n * 32 + j];
        if (off_feats >= 0) gA[off_feats + n * 32 + j] = v;
        if (Wn) {
            sH[ns][j] = v;
            __syncthreads();
            float acc = bb;
            #pragma unroll
            for (int k = 0; k < 32; k += 4) {
                float4 h4 = *(const float4*)&sH[ns][k];
                acc += h4.x * wc[k] + h4.y * wc[k + 1] + h4.z * wc[k + 2] + h4.w * wc[k + 3];
            }
            gA[off_out + n * 32 + j] = acc;
            s1 += acc; s2 += acc * acc;
            __syncthreads();
        }
    }
    if (Wn) {
        atomicAdd(&red[j], s1);
        atomicAdd(&red[j + 32], s2);
        __syncthreads();
        if (threadIdx.x < 64) atomicAdd(&gA[st_out + threadIdx.x], red[threadIdx.x]);
    }
}

// ---------------- msg prep: msgb = bf16(lrelu(BN(PA))) ----------------
__global__ __launch_bounds__(256) void k_msgp_v15(int st,
                                                  const float* __restrict__ gm,
                                                  const float* __restrict__ bem)
{
    __shared__ float sc[32], sh[32];
    int tid = threadIdx.x;
    if (tid < 32) {
        float mean = gA[st + tid] * (1.f / NN);
        float var  = gA[st + 32 + tid] * (1.f / NN) - mean * mean;
        float s = gm[tid] * rsqrtf(var + EPS);
        sc[tid] = s;
        sh[tid] = bem[tid] - mean * s;
    }
    __syncthreads();
    int idx = (blockIdx.x * 256 + tid) * 4;     // grid 3125 -> exactly NV
    float4 p = *(const float4*)(gA + OFF_PA + idx);
    int f = idx & 31;
    ushort4 o;
    o.x = f2b(lrelu(sc[f]     * p.x + sh[f]));
    o.y = f2b(lrelu(sc[f + 1] * p.y + sh[f + 1]));
    o.z = f2b(lrelu(sc[f + 2] * p.z + sh[f + 2]));
    o.w = f2b(lrelu(sc[f + 3] * p.w + sh[f + 3]));
    *(ushort4*)((unsigned short*)(gA + OFF_MSGB) + idx) = o;
}

// ---------------- CSR gather (bf16 msgs), 4-edge unrolled for MLP ----------------
__global__ __launch_bounds__(256) void k_gather_v15()
{
    int tid = threadIdx.x;
    int n = blockIdx.x * 32 + (tid >> 3);
    int g = tid & 7;
    int e0 = g_rowptr[n], e1 = g_rowptr[n + 1];
    const unsigned short* mb = (const unsigned short*)(gA + OFF_MSGB);
    float a0 = 0.f, a1 = 0.f, a2 = 0.f, a3 = 0.f;
    int e = e0;
    for (; e + 3 < e1; e += 4) {
        int s0 = g_csr[e];
        int s1 = g_csr[e + 1];
        int s2 = g_csr[e + 2];
        int s3 = g_csr[e + 3];
        ushort4 m0 = *(const ushort4*)(mb + s0 * 32 + g * 4);
        ushort4 m1 = *(const ushort4*)(mb + s1 * 32 + g * 4);
        ushort4 m2 = *(const ushort4*)(mb + s2 * 32 + g * 4);
        ushort4 m3 = *(const ushort4*)(mb + s3 * 32 + g * 4);
        a0 += (b2f(m0.x) + b2f(m1.x)) + (b2f(m2.x) + b2f(m3.x));
        a1 += (b2f(m0.y) + b2f(m1.y)) + (b2f(m2.y) + b2f(m3.y));
        a2 += (b2f(m0.z) + b2f(m1.z)) + (b2f(m2.z) + b2f(m3.z));
        a3 += (b2f(m0.w) + b2f(m1.w)) + (b2f(m2.w) + b2f(m3.w));
    }
    for (; e < e1; ++e) {
        int s0 = g_csr[e];
        ushort4 m0 = *(const ushort4*)(mb + s0 * 32 + g * 4);
        a0 += b2f(m0.x); a1 += b2f(m0.y); a2 += b2f(m0.z); a3 += b2f(m0.w);
    }
    *(float4*)(gA + OFF_AGG + n * 32 + g * 4) = make_float4(a0, a1, a2, a3);
}

// ---------------- update linear: PB = [h, agg] @ Wu + bu, stats ----------------
__global__ void k_upd_v15(int off_h, int off_out,
                          const float* __restrict__ Wu_i, const float* __restrict__ bu_i,
                          int st_out)
{
    int j = threadIdx.x & 31, ns = threadIdx.x >> 5;
    float wc[64];
    #pragma unroll
    for (int k = 0; k < 64; ++k) wc[k] = Wu_i[k * 32 + j];
    float bb = bu_i[j];
    __shared__ float sH[8][32];
    __shared__ float sA[8][32];
    __shared__ float red[64];
    if (threadIdx.x < 64) red[threadIdx.x] = 0.f;
    __syncthreads();
    float s1 = 0.f, s2 = 0.f;
    for (int t = blockIdx.x; t < NN / 8; t += gridDim.x) {
        int n = t * 8 + ns;
        sH[ns][j] = gA[off_h + n * 32 + j];
        sA[ns][j] = gA[OFF_AGG + n * 32 + j];
        __syncthreads();
        float acc = bb;
        #pragma unroll
        for (int k = 0; k < 32; k += 4) {
            float4 h4 = *(const float4*)&sH[ns][k];
            acc += h4.x * wc[k] + h4.y * wc[k + 1] + h4.z * wc[k + 2] + h4.w * wc[k + 3];
            float4 a4 = *(const float4*)&sA[ns][k];
            acc += a4.x * wc[32 + k] + a4.y * wc[32 + k + 1] + a4.z * wc[32 + k + 2] + a4.w * wc[32 + k + 3];
        }
        gA[off_out + n * 32 + j] = acc;
        s1 += acc; s2 += acc * acc;
        __syncthreads();
    }
    atomicAdd(&red[j], s1);
    atomicAdd(&red[j + 32], s2);
    __syncthreads();
    if (threadIdx.x < 64) atomicAdd(&gA[st_out + threadIdx.x], red[threadIdx.x]);
}

// ---------------- fused final MLP: 32 nodes/block, weight prefetch ----------------
__global__ __launch_bounds__(256) void k_final_v15(
    int off_h,
    const float* __restrict__ Wf0, const float* __restrict__ bf0,
    const float* __restrict__ Wf1, const float* __restrict__ bf1,
    const float* __restrict__ Wf2, const float* __restrict__ bf2,
    const float* __restrict__ Wf3, const float* __restrict__ bf3,
    const float* __restrict__ Wo,  const float* __restrict__ bo,
    float* __restrict__ out)
{
    __shared__ float sH[32][32];    // 4 KB
    __shared__ float sA[32][256];   // 32 KB (t0; cols 0..63 reused as t2)
    __shared__ float sB[32][128];   // 16 KB (t1; flat reused as t3)
    float* sBf = &sB[0][0];
    int tid = threadIdx.x;
    int base = blockIdx.x * 32;
    const float* hin = gA + off_h;

    for (int idx = tid; idx < 1024; idx += 256)
        sH[idx >> 5][idx & 31] = hin[base * 32 + idx];
    __syncthreads();

    // L0: 32->256, thread = output column
    {
        float w0[32];
        #pragma unroll
        for (int k = 0; k < 32; ++k) w0[k] = Wf0[k * 256 + tid];
        float bb = bf0[tid];
        for (int n = 0; n < 32; ++n) {
            float acc = bb;
            #pragma unroll
            for (int k = 0; k < 32; k += 4) {
                float4 h4 = *(const float4*)&sH[n][k];
                acc += h4.x * w0[k] + h4.y * w0[k + 1] + h4.z * w0[k + 2] + h4.w * w0[k + 3];
            }
            sA[n][tid] = lrelu(acc);
        }
    }
    __syncthreads();

    // L1: 256->128, thread: outputs {j, j+64}, 8 nodes; prefetched weights
    {
        int j = tid & 63, ng = tid >> 6;
        float acc0[8], acc1[8];
        float bb0 = bf1[j], bb1 = bf1[j + 64];
        #pragma unroll
        for (int q = 0; q < 8; ++q) { acc0[q] = bb0; acc1[q] = bb1; }
        float wa[4], wb[4];
        #pragma unroll
        for (int i = 0; i < 4; ++i) {
            wa[i] = Wf1[i * 128 + j];
            wb[i] = Wf1[i * 128 + j + 64];
        }
        for (int r4 = 0; r4 < 256; r4 += 4) {
            int rn = (r4 + 4) & 255;        // wraps to 0 on last iter (harmless reload)
            float na[4], nb[4];
            #pragma unroll
            for (int i = 0; i < 4; ++i) {
                na[i] = Wf1[(rn + i) * 128 + j];
                nb[i] = Wf1[(rn + i) * 128 + j + 64];
            }
            #pragma unroll
            for (int q = 0; q < 8; ++q) {
                float4 a4 = *(const float4*)&sA[ng * 8 + q][r4];
                acc0[q] += a4.x * wa[0] + a4.y * wa[1] + a4.z * wa[2] + a4.w * wa[3];
                acc1[q] += a4.x * wb[0] + a4.y * wb[1] + a4.z * wb[2] + a4.w * wb[3];
            }
            #pragma unroll
            for (int i = 0; i < 4; ++i) { wa[i] = na[i]; wb[i] = nb[i]; }
        }
        __syncthreads();
        #pragma unroll
        for (int q = 0; q < 8; ++q) {
            int n = ng * 8 + q;
            sB[n][j]      = lrelu(acc0[q]);
            sB[n][j + 64] = lrelu(acc1[q]);
        }
    }
    __syncthreads();

    // L2: 128->64, thread: output j, 8 nodes; prefetched weights
    {
        int j = tid & 63, ng = tid >> 6;
        float acc[8];
        float bb = bf2[j];
        #pragma unroll
        for (int q = 0; q < 8; ++q) acc[q] = bb;
        float w4[4];
        #pragma unroll
        for (int i = 0; i < 4; ++i) w4[i] = Wf2[i * 64 + j];
        for (int r4 = 0; r4 < 128; r4 += 4) {
            int rn = (r4 + 4) & 127;
            float nw[4];
            #pragma unroll
            for (int i = 0; i < 4; ++i) nw[i] = Wf2[(rn + i) * 64 + j];
            #pragma unroll
            for (int q = 0; q < 8; ++q) {
                float4 a4 = *(const float4*)&sB[ng * 8 + q][r4];
                acc[q] += a4.x * w4[0] + a4.y * w4[1] + a4.z * w4[2] + a4.w * w4[3];
            }
            #pragma unroll
            for (int i = 0; i < 4; ++i) w4[i] = nw[i];
        }
        __syncthreads();
        #pragma unroll
        for (int q = 0; q < 8; ++q)
            sA[ng * 8 + q][j] = lrelu(acc[q]);   // t2 in sA cols 0..63
    }
    __syncthreads();

    // L3: 64->32, thread: output j, 4 nodes
    {
        int j = tid & 31, ng = tid >> 5;
        float acc[4];
        float bb = bf3[j];
        #pragma unroll
        for (int q = 0; q < 4; ++q) acc[q] = bb;
        #pragma unroll
        for (int k4 = 0; k4 < 64; k4 += 4) {
            float w4[4];
            #pragma unroll
            for (int i = 0; i < 4; ++i) w4[i] = Wf3[(k4 + i) * 32 + j];
            #pragma unroll
            for (int q = 0; q < 4; ++q) {
                float4 a4 = *(const float4*)&sA[ng * 4 + q][k4];
                acc[q] += a4.x * w4[0] + a4.y * w4[1] + a4.z * w4[2] + a4.w * w4[3];
            }
        }
        __syncthreads();
        #pragma unroll
        for (int q = 0; q < 4; ++q)
            sBf[(ng * 4 + q) * 32 + j] = lrelu(acc[q]);  // t3 flat
    }
    __syncthreads();

    // Out: 32->1 + sigmoid; 8 lanes per node
    {
        int n = tid >> 3, p = tid & 7;
        const float* t3 = &sBf[n * 32];
        float s = 0.f;
        #pragma unroll
        for (int i = 0; i < 4; ++i) {
            int k = p * 4 + i;
            s += t3[k] * Wo[k];
        }
        s += __shfl_xor(s, 1);
        s += __shfl_xor(s, 2);
        s += __shfl_xor(s, 4);
        if (p == 0) {
            float z = s + bo[0];
            out[base + n] = 1.f / (1.f + __expf(-z));
        }
    }
}

extern "C" void kernel_launch(void* const* d_in, const int* in_sizes, int n_in,
                              void* d_out, int out_size, void* d_ws, size_t ws_size,
                              hipStream_t stream)
{
    (void)in_sizes; (void)n_in; (void)out_size; (void)d_ws; (void)ws_size;
    float* out = (float*)d_out;

    const float* x   = (const float*)d_in[0];
    const int*  col  = (const int*) d_in[1];
    const float* Wi0 = (const float*)d_in[2];
    const float* bi0 = (const float*)d_in[3];
    const float* gi0 = (const float*)d_in[4];
    const float* bei0= (const float*)d_in[5];
    const float* Wi1 = (const float*)d_in[6];
    const float* bi1 = (const float*)d_in[7];
    const float* gi1 = (const float*)d_in[8];
    const float* bei1= (const float*)d_in[9];
    const float* Wm  = (const float*)d_in[10];
    const float* bm  = (const float*)d_in[11];
    const float* gm  = (const float*)d_in[12];
    const float* bem = (const float*)d_in[13];
    const float* Wu  = (const float*)d_in[14];
    const float* bu  = (const float*)d_in[15];
    const float* gu  = (const float*)d_in[16];
    const float* beu = (const float*)d_in[17];
    const float* Wf0 = (const float*)d_in[18];
    const float* bf0 = (const float*)d_in[19];
    const float* Wf1 = (const float*)d_in[20];
    const float* bf1 = (const float*)d_in[21];
    const float* Wf2 = (const float*)d_in[22];
    const float* bf2 = (const float*)d_in[23];
    const float* Wf3 = (const float*)d_in[24];
    const float* bf3 = (const float*)d_in[25];
    const float* Wo  = (const float*)d_in[26];
    const float* bo  = (const float*)d_in[27];

    const int st_i0 = OFF_STATS;
    const int st_i1 = OFF_STATS + 64;
    const int st_m  = OFF_STATS + 128;   // + i*64
    const int st_u  = OFF_STATS + 768;   // + i*64

    const int RING[4] = { OFF_RING, OFF_RING + NV, OFF_RING + 2 * NV, OFF_RING + 3 * NV };

    dim3 blk(256);
    k_zero_v15<<<NBLK, blk, 0, stream>>>();
    k_count_v15<<<6250, blk, 0, stream>>>(col);
    k_bsum_v15<<<NBLK, blk, 0, stream>>>();
    k_bscan_v15<<<1, 512, 0, stream>>>();
    k_bexp_v15<<<NBLK, blk, 0, stream>>>();
    k_fill_v15<<<6250, blk, 0, stream>>>(col);

    // init MLP: x -> h0 (ring[0]); k_nl chains the msg linear of layer 0 into PA
    k_init0_v15<<<3125, blk, 0, stream>>>(x, Wi0, bi0);
    k_nl_v15<<<3125, blk, 0, stream>>>(OFF_PA, OFF_PB, st_i0, gi0, bei0, -1, -1, Wi1, bi1, st_i1);
    k_nl_v15<<<3125, blk, 0, stream>>>(OFF_PB, OFF_PA, st_i1, gi1, bei1, -1, RING[0], Wm, bm, st_m);

    for (int i = 0; i < 10; ++i) {
        int h_cur = RING[i & 3];
        int h_new = RING[(i + 1) & 3];
        int resid = (i >= 2) ? RING[(i - 2) & 3] : -1;
        k_msgp_v15<<<3125, blk, 0, stream>>>(st_m + i * 64, gm + i * 32, bem + i * 32);
        k_gather_v15<<<3125, blk, 0, stream>>>();
        k_upd_v15<<<3125, blk, 0, stream>>>(h_cur, OFF_PB, Wu + i * 2048, bu + i * 32, st_u + i * 64);
        const float* Wn = (i < 9) ? (Wm + (i + 1) * 1024) : nullptr;
        const float* bn = (i < 9) ? (bm + (i + 1) * 32) : nullptr;
        int st_next = (i < 9) ? (st_m + (i + 1) * 64) : 0;
        k_nl_v15<<<3125, blk, 0, stream>>>(OFF_PB, OFF_PA, st_u + i * 64, gu + i * 32, beu + i * 32,
                                           resid, h_new, Wn, bn, st_next);
    }

    k_final_v15<<<3125, blk, 0, stream>>>(RING[2], Wf0, bf0, Wf1, bf1, Wf2, bf2,
                                          Wf3, bf3, Wo, bo, out);
}

// Round 16
// 1361.228 us; speedup vs baseline: 2.0295x; 2.0295x over previous
//
#include <hip/hip_runtime.h>
#include <hip/hip_bf16.h>

#define NN 100000
#define NEDGE 1600000
#define NV (NN*32)
#define NEG 0.01f
#define EPS 1e-5f
#define NBLK 391            // ceil(NN/256)
#define STC 64              // stat copies (contention spread)
#define ST_STRIDE 4096      // STC * 64

// ---- static device arena (fp32) ----
#define OFF_STATS 0
#define STATS_F  (22*ST_STRIDE)          // 22 stat slots x 64 copies x 64 floats
#define OFF_PA   STATS_F
#define OFF_PB   (OFF_PA + NV)
#define OFF_AGG  (OFF_PB + NV)
#define OFF_MSGB (OFF_AGG + NV)          // NV bf16 = NV/2 floats
#define OFF_RING (OFF_MSGB + NV/2)
#define ARENA_F  (OFF_RING + 4*NV)

__device__ __align__(16) float gA[ARENA_F];
__device__ int g_cnt[NN];
__device__ int g_rowptr[NN + 1];
__device__ int g_cur[NN];
__device__ int g_csr[NEDGE];
__device__ int g_bsum[NBLK];
__device__ int g_boff[NBLK];

__device__ __forceinline__ float lrelu(float v) { return v > 0.f ? v : v * NEG; }
__device__ __forceinline__ unsigned short f2b(float v) {
    __hip_bfloat16 b = __float2bfloat16(v);
    return *reinterpret_cast<unsigned short*>(&b);
}
__device__ __forceinline__ float b2f(unsigned short u) {
    __hip_bfloat16 b = *reinterpret_cast<__hip_bfloat16*>(&u);
    return __bfloat162float(b);
}

// ---------------- zero stats + counts ----------------
__global__ void k_zero_v16()
{
    int i = blockIdx.x * 256 + threadIdx.x;
    if (i < STATS_F) gA[i] = 0.f;
    if (i < NN) g_cnt[i] = 0;
}

// ---------------- CSR build ----------------
__global__ void k_count_v16(const int* __restrict__ col)
{
    int e = blockIdx.x * 256 + threadIdx.x;
    if (e < NEDGE) atomicAdd(&g_cnt[col[NEDGE + e]], 1);
}

__global__ __launch_bounds__(256) void k_bsum_v16()
{
    __shared__ int s[256];
    int i = blockIdx.x * 256 + threadIdx.x;
    int v = (i < NN) ? g_cnt[i] : 0;
    s[threadIdx.x] = v;
    __syncthreads();
    for (int off = 128; off > 0; off >>= 1) {
        if (threadIdx.x < off) s[threadIdx.x] += s[threadIdx.x + off];
        __syncthreads();
    }
    if (threadIdx.x == 0) g_bsum[blockIdx.x] = s[0];
}

__global__ __launch_bounds__(512) void k_bscan_v16()
{
    __shared__ int s[512];
    int t = threadIdx.x;
    int v = (t < NBLK) ? g_bsum[t] : 0;
    s[t] = v;
    __syncthreads();
    for (int off = 1; off < 512; off <<= 1) {
        int u = (t >= off) ? s[t - off] : 0;
        __syncthreads();
        s[t] += u;
        __syncthreads();
    }
    if (t < NBLK) g_boff[t] = s[t] - v;
    if (t == NBLK - 1) g_rowptr[NN] = s[t];
}

__global__ __launch_bounds__(256) void k_bexp_v16()
{
    __shared__ int s[256];
    int i = blockIdx.x * 256 + threadIdx.x;
    int t = threadIdx.x;
    int v = (i < NN) ? g_cnt[i] : 0;
    s[t] = v;
    __syncthreads();
    for (int off = 1; off < 256; off <<= 1) {
        int u = (t >= off) ? s[t - off] : 0;
        __syncthreads();
        s[t] += u;
        __syncthreads();
    }
    if (i < NN) {
        int p = g_boff[blockIdx.x] + s[t] - v;
        g_rowptr[i] = p;
        g_cur[i] = p;
    }
}

__global__ void k_fill_v16(const int* __restrict__ col)
{
    int e = blockIdx.x * 256 + threadIdx.x;
    if (e >= NEDGE) return;
    int s = col[e];
    int d = col[NEDGE + e];
    int pos = atomicAdd(&g_cur[d], 1);
    g_csr[pos] = s;
}

// ---------------- init layer 0: PA = x*Wi0 + bi0, stats ----------------
__global__ void k_init0_v16(const float* __restrict__ x, const float* __restrict__ Wi0,
                            const float* __restrict__ bi0)
{
    int j = threadIdx.x & 31, ns = threadIdx.x >> 5;
    float w = Wi0[j];
    float bb = bi0[j];
    __shared__ float red[64];
    if (threadIdx.x < 64) red[threadIdx.x] = 0.f;
    __syncthreads();
    float s1 = 0.f, s2 = 0.f;
    for (int t = blockIdx.x; t < NN / 8; t += gridDim.x) {
        int n = t * 8 + ns;
        float v = x[n] * w + bb;
        gA[OFF_PA + n * 32 + j] = v;
        s1 += v; s2 += v * v;
    }
    atomicAdd(&red[j], s1);
    atomicAdd(&red[j + 32], s2);
    __syncthreads();
    if (threadIdx.x < 64)
        atomicAdd(&gA[OFF_STATS + (blockIdx.x & (STC - 1)) * 64 + threadIdx.x], red[threadIdx.x]);
}

// ------- BN+LReLU (+resid) (+feats store) (+fused next 32x32 linear + stats) -------
__global__ void k_nl_v16(int off_in, int off_out, int st_in,
                         const float* __restrict__ gamma, const float* __restrict__ beta,
                         int off_resid, int off_feats,
                         const float* __restrict__ Wn, const float* __restrict__ bn,
                         int st_out)
{
    int j = threadIdx.x & 31, ns = threadIdx.x >> 5;
    __shared__ float sstat[64];
    __shared__ float red[64];
    if (threadIdx.x < 64) {
        red[threadIdx.x] = 0.f;
        float acc = 0.f;
        int base = st_in + (threadIdx.x >= 32 ? 32 : 0) + (threadIdx.x & 31);
        #pragma unroll 8
        for (int c = 0; c < STC; ++c) acc += gA[base + c * 64];
        sstat[threadIdx.x] = acc;
    }
    __syncthreads();
    float mean = sstat[j] * (1.f / NN);
    float var  = sstat[32 + j] * (1.f / NN) - mean * mean;
    float scale = gamma[j] * rsqrtf(var + EPS);
    float shift = beta[j] - mean * scale;

    float wc[32]; float bb = 0.f;
    if (Wn) {
        #pragma unroll
        for (int k = 0; k < 32; ++k) wc[k] = Wn[k * 32 + j];
        bb = bn[j];
    }
    __shared__ float sH[8][32];
    float s1 = 0.f, s2 = 0.f;
    for (int t = blockIdx.x; t < NN / 8; t += gridDim.x) {
        int n = t * 8 + ns;
        float v = gA[off_in + n * 32 + j];
        v = lrelu(scale * v + shift);
        if (off_resid >= 0) v += gA[off_resid + n * 32 + j];
        if (off_feats >= 0) gA[off_feats + n * 32 + j] = v;
        if (Wn) {
            sH[ns][j] = v;
            __syncthreads();
            float acc = bb;
            #pragma unroll
            for (int k = 0; k < 32; k += 4) {
                float4 h4 = *(const float4*)&sH[ns][k];
                acc += h4.x * wc[k] + h4.y * wc[k + 1] + h4.z * wc[k + 2] + h4.w * wc[k + 3];
            }
            gA[off_out + n * 32 + j] = acc;
            s1 += acc; s2 += acc * acc;
            __syncthreads();
        }
    }
    if (Wn) {
        atomicAdd(&red[j], s1);
        atomicAdd(&red[j + 32], s2);
        __syncthreads();
        if (threadIdx.x < 64)
            atomicAdd(&gA[st_out + (blockIdx.x & (STC - 1)) * 64 + threadIdx.x], red[threadIdx.x]);
    }
}

// ---------------- msg prep: msgb = bf16(lrelu(BN(PA))) ----------------
__global__ __launch_bounds__(256) void k_msgp_v16(int st,
                                                  const float* __restrict__ gm,
                                                  const float* __restrict__ bem)
{
    __shared__ float sstat[64];
    __shared__ float sc[32], sh[32];
    int tid = threadIdx.x;
    if (tid < 64) {
        float acc = 0.f;
        int base = st + (tid >= 32 ? 32 : 0) + (tid & 31);
        #pragma unroll 8
        for (int c = 0; c < STC; ++c) acc += gA[base + c * 64];
        sstat[tid] = acc;
    }
    __syncthreads();
    if (tid < 32) {
        float mean = sstat[tid] * (1.f / NN);
        float var  = sstat[32 + tid] * (1.f / NN) - mean * mean;
        float s = gm[tid] * rsqrtf(var + EPS);
        sc[tid] = s;
        sh[tid] = bem[tid] - mean * s;
    }
    __syncthreads();
    int idx = (blockIdx.x * 256 + tid) * 4;     // grid 3125 -> exactly NV
    float4 p = *(const float4*)(gA + OFF_PA + idx);
    int f = idx & 31;
    ushort4 o;
    o.x = f2b(lrelu(sc[f]     * p.x + sh[f]));
    o.y = f2b(lrelu(sc[f + 1] * p.y + sh[f + 1]));
    o.z = f2b(lrelu(sc[f + 2] * p.z + sh[f + 2]));
    o.w = f2b(lrelu(sc[f + 3] * p.w + sh[f + 3]));
    *(ushort4*)((unsigned short*)(gA + OFF_MSGB) + idx) = o;
}

// ---------------- CSR gather (bf16 msgs), 2-edge pipelined ----------------
__global__ __launch_bounds__(256) void k_gather_v16()
{
    int tid = threadIdx.x;
    int n = blockIdx.x * 32 + (tid >> 3);
    int g = tid & 7;
    int e0 = g_rowptr[n], e1 = g_rowptr[n + 1];
    const unsigned short* mb = (const unsigned short*)(gA + OFF_MSGB);
    float a0 = 0.f, a1 = 0.f, a2 = 0.f, a3 = 0.f;
    int e = e0;
    for (; e + 1 < e1; e += 2) {
        int s0 = g_csr[e];
        int s1 = g_csr[e + 1];
        ushort4 m0 = *(const ushort4*)(mb + s0 * 32 + g * 4);
        ushort4 m1 = *(const ushort4*)(mb + s1 * 32 + g * 4);
        a0 += b2f(m0.x) + b2f(m1.x);
        a1 += b2f(m0.y) + b2f(m1.y);
        a2 += b2f(m0.z) + b2f(m1.z);
        a3 += b2f(m0.w) + b2f(m1.w);
    }
    if (e < e1) {
        int s0 = g_csr[e];
        ushort4 m0 = *(const ushort4*)(mb + s0 * 32 + g * 4);
        a0 += b2f(m0.x); a1 += b2f(m0.y); a2 += b2f(m0.z); a3 += b2f(m0.w);
    }
    *(float4*)(gA + OFF_AGG + n * 32 + g * 4) = make_float4(a0, a1, a2, a3);
}

// ---------------- update linear: PB = [h, agg] @ Wu + bu, stats ----------------
__global__ void k_upd_v16(int off_h, int off_out,
                          const float* __restrict__ Wu_i, const float* __restrict__ bu_i,
                          int st_out)
{
    int j = threadIdx.x & 31, ns = threadIdx.x >> 5;
    float wc[64];
    #pragma unroll
    for (int k = 0; k < 64; ++k) wc[k] = Wu_i[k * 32 + j];
    float bb = bu_i[j];
    __shared__ float sH[8][32];
    __shared__ float sA[8][32];
    __shared__ float red[64];
    if (threadIdx.x < 64) red[threadIdx.x] = 0.f;
    __syncthreads();
    float s1 = 0.f, s2 = 0.f;
    for (int t = blockIdx.x; t < NN / 8; t += gridDim.x) {
        int n = t * 8 + ns;
        sH[ns][j] = gA[off_h + n * 32 + j];
        sA[ns][j] = gA[OFF_AGG + n * 32 + j];
        __syncthreads();
        float acc = bb;
        #pragma unroll
        for (int k = 0; k < 32; k += 4) {
            float4 h4 = *(const float4*)&sH[ns][k];
            acc += h4.x * wc[k] + h4.y * wc[k + 1] + h4.z * wc[k + 2] + h4.w * wc[k + 3];
            float4 a4 = *(const float4*)&sA[ns][k];
            acc += a4.x * wc[32 + k] + a4.y * wc[32 + k + 1] + a4.z * wc[32 + k + 2] + a4.w * wc[32 + k + 3];
        }
        gA[off_out + n * 32 + j] = acc;
        s1 += acc; s2 += acc * acc;
        __syncthreads();
    }
    atomicAdd(&red[j], s1);
    atomicAdd(&red[j + 32], s2);
    __syncthreads();
    if (threadIdx.x < 64)
        atomicAdd(&gA[st_out + (blockIdx.x & (STC - 1)) * 64 + threadIdx.x], red[threadIdx.x]);
}

// ---------------- fused final MLP: 32 nodes/block, NO sW staging (52 KB LDS) ----------------
__global__ __launch_bounds__(256) void k_final_v16(
    int off_h,
    const float* __restrict__ Wf0, const float* __restrict__ bf0,
    const float* __restrict__ Wf1, const float* __restrict__ bf1,
    const float* __restrict__ Wf2, const float* __restrict__ bf2,
    const float* __restrict__ Wf3, const float* __restrict__ bf3,
    const float* __restrict__ Wo,  const float* __restrict__ bo,
    float* __restrict__ out)
{
    __shared__ float sH[32][32];    // 4 KB
    __shared__ float sA[32][256];   // 32 KB (t0; cols 0..63 reused as t2)
    __shared__ float sB[32][128];   // 16 KB (t1; flat reused as t3)
    float* sBf = &sB[0][0];
    int tid = threadIdx.x;
    int base = blockIdx.x * 32;
    const float* hin = gA + off_h;

    for (int idx = tid; idx < 1024; idx += 256)
        sH[idx >> 5][idx & 31] = hin[base * 32 + idx];
    __syncthreads();

    // L0: 32->256
    {
        float w0[32];
        #pragma unroll
        for (int k = 0; k < 32; ++k) w0[k] = Wf0[k * 256 + tid];
        float bb = bf0[tid];
        for (int n = 0; n < 32; ++n) {
            float acc = bb;
            #pragma unroll
            for (int k = 0; k < 32; k += 4) {
                float4 h4 = *(const float4*)&sH[n][k];
                acc += h4.x * w0[k] + h4.y * w0[k + 1] + h4.z * w0[k + 2] + h4.w * w0[k + 3];
            }
            sA[n][tid] = lrelu(acc);
        }
    }
    __syncthreads();

    // L1: 256->128
    {
        int j = tid & 63, ng = tid >> 6;
        float acc0[8], acc1[8];
        float bb0 = bf1[j], bb1 = bf1[j + 64];
        #pragma unroll
        for (int q = 0; q < 8; ++q) { acc0[q] = bb0; acc1[q] = bb1; }
        for (int r4 = 0; r4 < 256; r4 += 4) {
            float wa[4], wb[4];
            #pragma unroll
            for (int i = 0; i < 4; ++i) {
                wa[i] = Wf1[(r4 + i) * 128 + j];
                wb[i] = Wf1[(r4 + i) * 128 + j + 64];
            }
            #pragma unroll
            for (int q = 0; q < 8; ++q) {
                float4 a4 = *(const float4*)&sA[ng * 8 + q][r4];
                acc0[q] += a4.x * wa[0] + a4.y * wa[1] + a4.z * wa[2] + a4.w * wa[3];
                acc1[q] += a4.x * wb[0] + a4.y * wb[1] + a4.z * wb[2] + a4.w * wb[3];
            }
        }
        __syncthreads();
        #pragma unroll
        for (int q = 0; q < 8; ++q) {
            int n = ng * 8 + q;
            sB[n][j]      = lrelu(acc0[q]);
            sB[n][j + 64] = lrelu(acc1[q]);
        }
    }
    __syncthreads();

    // L2: 128->64
    {
        int j = tid & 63, ng = tid >> 6;
        float acc[8];
        float bb = bf2[j];
        #pragma unroll
        for (int q = 0; q < 8; ++q) acc[q] = bb;
        for (int r4 = 0; r4 < 128; r4 += 4) {
            float w4[4];
            #pragma unroll
            for (int i = 0; i < 4; ++i) w4[i] = Wf2[(r4 + i) * 64 + j];
            #pragma unroll
            for (int q = 0; q < 8; ++q) {
                float4 a4 = *(const float4*)&sB[ng * 8 + q][r4];
                acc[q] += a4.x * w4[0] + a4.y * w4[1] + a4.z * w4[2] + a4.w * w4[3];
            }
        }
        __syncthreads();
        #pragma unroll
        for (int q = 0; q < 8; ++q)
            sA[ng * 8 + q][j] = lrelu(acc[q]);   // t2 in sA cols 0..63
    }
    __syncthreads();

    // L3: 64->32
    {
        int j = tid & 31, ng = tid >> 5;
        float acc[4];
        float bb = bf3[j];
        #pragma unroll
        for (int q = 0; q < 4; ++q) acc[q] = bb;
        #pragma unroll
        for (int k4 = 0; k4 < 64; k4 += 4) {
            float w4[4];
            #pragma unroll
            for (int i = 0; i < 4; ++i) w4[i] = Wf3[(k4 + i) * 32 + j];
            #pragma unroll
            for (int q = 0; q < 4; ++q) {
                float4 a4 = *(const float4*)&sA[ng * 4 + q][k4];
                acc[q] += a4.x * w4[0] + a4.y * w4[1] + a4.z * w4[2] + a4.w * w4[3];
            }
        }
        __syncthreads();
        #pragma unroll
        for (int q = 0; q < 4; ++q)
            sBf[(ng * 4 + q) * 32 + j] = lrelu(acc[q]);  // t3 flat
    }
    __syncthreads();

    // Out: 32->1 + sigmoid; 8 lanes per node
    {
        int n = tid >> 3, p = tid & 7;
        const float* t3 = &sBf[n * 32];
        float s = 0.f;
        #pragma unroll
        for (int i = 0; i < 4; ++i) {
            int k = p * 4 + i;
            s += t3[k] * Wo[k];
        }
        s += __shfl_xor(s, 1);
        s += __shfl_xor(s, 2);
        s += __shfl_xor(s, 4);
        if (p == 0) {
            float z = s + bo[0];
            out[base + n] = 1.f / (1.f + __expf(-z));
        }
    }
}

extern "C" void kernel_launch(void* const* d_in, const int* in_sizes, int n_in,
                              void* d_out, int out_size, void* d_ws, size_t ws_size,
                              hipStream_t stream)
{
    (void)in_sizes; (void)n_in; (void)out_size; (void)d_ws; (void)ws_size;
    float* out = (float*)d_out;

    const float* x   = (const float*)d_in[0];
    const int*  col  = (const int*) d_in[1];
    const float* Wi0 = (const float*)d_in[2];
    const float* bi0 = (const float*)d_in[3];
    const float* gi0 = (const float*)d_in[4];
    const float* bei0= (const float*)d_in[5];
    const float* Wi1 = (const float*)d_in[6];
    const float* bi1 = (const float*)d_in[7];
    const float* gi1 = (const float*)d_in[8];
    const float* bei1= (const float*)d_in[9];
    const float* Wm  = (const float*)d_in[10];
    const float* bm  = (const float*)d_in[11];
    const float* gm  = (const float*)d_in[12];
    const float* bem = (const float*)d_in[13];
    const float* Wu  = (const float*)d_in[14];
    const float* bu  = (const float*)d_in[15];
    const float* gu  = (const float*)d_in[16];
    const float* beu = (const float*)d_in[17];
    const float* Wf0 = (const float*)d_in[18];
    const float* bf0 = (const float*)d_in[19];
    const float* Wf1 = (const float*)d_in[20];
    const float* bf1 = (const float*)d_in[21];
    const float* Wf2 = (const float*)d_in[22];
    const float* bf2 = (const float*)d_in[23];
    const float* Wf3 = (const float*)d_in[24];
    const float* bf3 = (const float*)d_in[25];
    const float* Wo  = (const float*)d_in[26];
    const float* bo  = (const float*)d_in[27];

    const int st_i0 = OFF_STATS;
    const int st_i1 = OFF_STATS + ST_STRIDE;
    const int st_m  = OFF_STATS + 2 * ST_STRIDE;    // + i*ST_STRIDE
    const int st_u  = OFF_STATS + 12 * ST_STRIDE;   // + i*ST_STRIDE

    const int RING[4] = { OFF_RING, OFF_RING + NV, OFF_RING + 2 * NV, OFF_RING + 3 * NV };

    dim3 blk(256);
    k_zero_v16<<<NBLK, blk, 0, stream>>>();
    k_count_v16<<<6250, blk, 0, stream>>>(col);
    k_bsum_v16<<<NBLK, blk, 0, stream>>>();
    k_bscan_v16<<<1, 512, 0, stream>>>();
    k_bexp_v16<<<NBLK, blk, 0, stream>>>();
    k_fill_v16<<<6250, blk, 0, stream>>>(col);

    // init MLP: x -> h0 (ring[0]); k_nl chains the msg linear of layer 0 into PA
    k_init0_v16<<<1024, blk, 0, stream>>>(x, Wi0, bi0);
    k_nl_v16<<<1024, blk, 0, stream>>>(OFF_PA, OFF_PB, st_i0, gi0, bei0, -1, -1, Wi1, bi1, st_i1);
    k_nl_v16<<<1024, blk, 0, stream>>>(OFF_PB, OFF_PA, st_i1, gi1, bei1, -1, RING[0], Wm, bm, st_m);

    for (int i = 0; i < 10; ++i) {
        int h_cur = RING[i & 3];
        int h_new = RING[(i + 1) & 3];
        int resid = (i >= 2) ? RING[(i - 2) & 3] : -1;
        k_msgp_v16<<<3125, blk, 0, stream>>>(st_m + i * ST_STRIDE, gm + i * 32, bem + i * 32);
        k_gather_v16<<<3125, blk, 0, stream>>>();
        k_upd_v16<<<1024, blk, 0, stream>>>(h_cur, OFF_PB, Wu + i * 2048, bu + i * 32,
                                            st_u + i * ST_STRIDE);
        const float* Wn = (i < 9) ? (Wm + (i + 1) * 1024) : nullptr;
        const float* bn = (i < 9) ? (bm + (i + 1) * 32) : nullptr;
        int st_next = (i < 9) ? (st_m + (i + 1) * ST_STRIDE) : 0;
        k_nl_v16<<<1024, blk, 0, stream>>>(OFF_PB, OFF_PA, st_u + i * ST_STRIDE,
                                           gu + i * 32, beu + i * 32,
                                           resid, h_new, Wn, bn, st_next);
    }

    k_final_v16<<<3125, blk, 0, stream>>>(RING[2], Wf0, bf0, Wf1, bf1, Wf2, bf2,
                                          Wf3, bf3, Wo, bo, out);
}

// Round 17
// 1288.969 us; speedup vs baseline: 2.1433x; 1.0561x over previous
//
#include <hip/hip_runtime.h>
#include <hip/hip_bf16.h>

#define NN 100000
#define NEDGE 1600000
#define NV (NN*32)
#define NEG 0.01f
#define EPS 1e-5f
#define NBLK 391            // ceil(NN/256)
#define STC 64              // stat copies (contention spread)
#define ST_STRIDE 4096      // STC * 64

// ---- static device arena (fp32) ----
#define OFF_STATS 0
#define STATS_F  (22*ST_STRIDE)
#define OFF_PA   STATS_F
#define OFF_PB   (OFF_PA + NV)
#define OFF_AGG  (OFF_PB + NV)
#define OFF_MSGB (OFF_AGG + NV)          // NV bf16 = NV/2 floats
#define OFF_RING (OFF_MSGB + NV/2)
#define ARENA_F  (OFF_RING + 4*NV)

__device__ __align__(16) float gA[ARENA_F];
__device__ int g_cnt[NN];
__device__ int g_rowptr[NN + 1];
__device__ int g_cur[NN];
__device__ int g_csr[NEDGE];
__device__ int g_bsum[NBLK];
__device__ int g_boff[NBLK];

__device__ __forceinline__ float lrelu(float v) { return v > 0.f ? v : v * NEG; }
__device__ __forceinline__ unsigned short f2b(float v) {
    __hip_bfloat16 b = __float2bfloat16(v);
    return *reinterpret_cast<unsigned short*>(&b);
}
__device__ __forceinline__ float b2f(unsigned short u) {
    __hip_bfloat16 b = *reinterpret_cast<__hip_bfloat16*>(&u);
    return __bfloat162float(b);
}

// ---------------- zero stats + counts ----------------
__global__ void k_zero_v17()
{
    int i = blockIdx.x * 256 + threadIdx.x;
    if (i < STATS_F) gA[i] = 0.f;
    if (i < NN) g_cnt[i] = 0;
}

// ---------------- CSR build ----------------
__global__ void k_count_v17(const int* __restrict__ col)
{
    int e = blockIdx.x * 256 + threadIdx.x;
    if (e < NEDGE) atomicAdd(&g_cnt[col[NEDGE + e]], 1);
}

__global__ __launch_bounds__(256) void k_bsum_v17()
{
    __shared__ int s[256];
    int i = blockIdx.x * 256 + threadIdx.x;
    int v = (i < NN) ? g_cnt[i] : 0;
    s[threadIdx.x] = v;
    __syncthreads();
    for (int off = 128; off > 0; off >>= 1) {
        if (threadIdx.x < off) s[threadIdx.x] += s[threadIdx.x + off];
        __syncthreads();
    }
    if (threadIdx.x == 0) g_bsum[blockIdx.x] = s[0];
}

__global__ __launch_bounds__(512) void k_bscan_v17()
{
    __shared__ int s[512];
    int t = threadIdx.x;
    int v = (t < NBLK) ? g_bsum[t] : 0;
    s[t] = v;
    __syncthreads();
    for (int off = 1; off < 512; off <<= 1) {
        int u = (t >= off) ? s[t - off] : 0;
        __syncthreads();
        s[t] += u;
        __syncthreads();
    }
    if (t < NBLK) g_boff[t] = s[t] - v;
    if (t == NBLK - 1) g_rowptr[NN] = s[t];
}

__global__ __launch_bounds__(256) void k_bexp_v17()
{
    __shared__ int s[256];
    int i = blockIdx.x * 256 + threadIdx.x;
    int t = threadIdx.x;
    int v = (i < NN) ? g_cnt[i] : 0;
    s[t] = v;
    __syncthreads();
    for (int off = 1; off < 256; off <<= 1) {
        int u = (t >= off) ? s[t - off] : 0;
        __syncthreads();
        s[t] += u;
        __syncthreads();
    }
    if (i < NN) {
        int p = g_boff[blockIdx.x] + s[t] - v;
        g_rowptr[i] = p;
        g_cur[i] = p;
    }
}

__global__ void k_fill_v17(const int* __restrict__ col)
{
    int e = blockIdx.x * 256 + threadIdx.x;
    if (e >= NEDGE) return;
    int s = col[e];
    int d = col[NEDGE + e];
    int pos = atomicAdd(&g_cur[d], 1);
    g_csr[pos] = s;
}

// ---------------- init layer 0: PA = x*Wi0 + bi0, stats ----------------
__global__ void k_init0_v17(const float* __restrict__ x, const float* __restrict__ Wi0,
                            const float* __restrict__ bi0)
{
    int j = threadIdx.x & 31, ns = threadIdx.x >> 5;
    float w = Wi0[j];
    float bb = bi0[j];
    __shared__ float red[64];
    if (threadIdx.x < 64) red[threadIdx.x] = 0.f;
    __syncthreads();
    float s1 = 0.f, s2 = 0.f;
    for (int t = blockIdx.x; t < NN / 8; t += gridDim.x) {
        int n = t * 8 + ns;
        float v = x[n] * w + bb;
        gA[OFF_PA + n * 32 + j] = v;
        s1 += v; s2 += v * v;
    }
    atomicAdd(&red[j], s1);
    atomicAdd(&red[j + 32], s2);
    __syncthreads();
    if (threadIdx.x < 64)
        atomicAdd(&gA[OFF_STATS + (blockIdx.x & (STC - 1)) * 64 + threadIdx.x], red[threadIdx.x]);
}

// ------- BN+LReLU (+resid) (+feats store) (+fused next 32x32 linear + stats) -------
// out_msg: if nonzero, fused-linear pre-acts are stored as bf16 into MSGB (else fp32 to off_out).
__global__ void k_nl_v17(int off_in, int off_out, int out_msg, int st_in,
                         const float* __restrict__ gamma, const float* __restrict__ beta,
                         int off_resid, int off_feats,
                         const float* __restrict__ Wn, const float* __restrict__ bn,
                         int st_out)
{
    int j = threadIdx.x & 31, ns = threadIdx.x >> 5;
    __shared__ float sstat[64];
    __shared__ float red[64];
    if (threadIdx.x < 64) {
        red[threadIdx.x] = 0.f;
        float acc = 0.f;
        int base = st_in + threadIdx.x;
        #pragma unroll 8
        for (int c = 0; c < STC; ++c) acc += gA[base + c * 64];
        sstat[threadIdx.x] = acc;
    }
    __syncthreads();
    float mean = sstat[j] * (1.f / NN);
    float var  = sstat[32 + j] * (1.f / NN) - mean * mean;
    float scale = gamma[j] * rsqrtf(var + EPS);
    float shift = beta[j] - mean * scale;

    float wc[32]; float bb = 0.f;
    if (Wn) {
        #pragma unroll
        for (int k = 0; k < 32; ++k) wc[k] = Wn[k * 32 + j];
        bb = bn[j];
    }
    unsigned short* mb = (unsigned short*)(gA + OFF_MSGB);
    __shared__ float sH[8][32];
    float s1 = 0.f, s2 = 0.f;
    for (int t = blockIdx.x; t < NN / 8; t += gridDim.x) {
        int n = t * 8 + ns;
        float v = gA[off_in + n * 32 + j];
        v = lrelu(scale * v + shift);
        if (off_resid >= 0) v += gA[off_resid + n * 32 + j];
        if (off_feats >= 0) gA[off_feats + n * 32 + j] = v;
        if (Wn) {
            sH[ns][j] = v;
            __syncthreads();
            float acc = bb;
            #pragma unroll
            for (int k = 0; k < 32; k += 4) {
                float4 h4 = *(const float4*)&sH[ns][k];
                acc += h4.x * wc[k] + h4.y * wc[k + 1] + h4.z * wc[k + 2] + h4.w * wc[k + 3];
            }
            if (out_msg) mb[n * 32 + j] = f2b(acc);
            else gA[off_out + n * 32 + j] = acc;
            s1 += acc; s2 += acc * acc;
            __syncthreads();
        }
    }
    if (Wn) {
        atomicAdd(&red[j], s1);
        atomicAdd(&red[j + 32], s2);
        __syncthreads();
        if (threadIdx.x < 64)
            atomicAdd(&gA[st_out + (blockIdx.x & (STC - 1)) * 64 + threadIdx.x], red[threadIdx.x]);
    }
}

// ---------------- CSR gather with fused msg BN+LReLU (bf16 pre-acts), 4-edge unroll ----------------
__global__ __launch_bounds__(256) void k_gather_v17(int st,
                                                    const float* __restrict__ gm,
                                                    const float* __restrict__ bem)
{
    __shared__ float sstat[64];
    __shared__ float sc[32], sh[32];
    int tid = threadIdx.x;
    if (tid < 64) {
        float acc = 0.f;
        int base = st + tid;
        #pragma unroll 8
        for (int c = 0; c < STC; ++c) acc += gA[base + c * 64];
        sstat[tid] = acc;
    }
    __syncthreads();
    if (tid < 32) {
        float mean = sstat[tid] * (1.f / NN);
        float var  = sstat[32 + tid] * (1.f / NN) - mean * mean;
        float s = gm[tid] * rsqrtf(var + EPS);
        sc[tid] = s;
        sh[tid] = bem[tid] - mean * s;
    }
    __syncthreads();
    int n = blockIdx.x * 32 + (tid >> 3);
    int g = tid & 7;
    int e0 = g_rowptr[n], e1 = g_rowptr[n + 1];
    const unsigned short* mb = (const unsigned short*)(gA + OFF_MSGB);
    float c0 = sc[g*4], c1 = sc[g*4+1], c2 = sc[g*4+2], c3 = sc[g*4+3];
    float h0 = sh[g*4], h1 = sh[g*4+1], h2 = sh[g*4+2], h3 = sh[g*4+3];
    float a0 = 0.f, a1 = 0.f, a2 = 0.f, a3 = 0.f;
    int e = e0;
    for (; e + 3 < e1; e += 4) {
        int s0 = g_csr[e];
        int s1 = g_csr[e + 1];
        int s2 = g_csr[e + 2];
        int s3 = g_csr[e + 3];
        ushort4 m0 = *(const ushort4*)(mb + s0 * 32 + g * 4);
        ushort4 m1 = *(const ushort4*)(mb + s1 * 32 + g * 4);
        ushort4 m2 = *(const ushort4*)(mb + s2 * 32 + g * 4);
        ushort4 m3 = *(const ushort4*)(mb + s3 * 32 + g * 4);
        a0 += lrelu(c0 * b2f(m0.x) + h0) + lrelu(c0 * b2f(m1.x) + h0)
            + lrelu(c0 * b2f(m2.x) + h0) + lrelu(c0 * b2f(m3.x) + h0);
        a1 += lrelu(c1 * b2f(m0.y) + h1) + lrelu(c1 * b2f(m1.y) + h1)
            + lrelu(c1 * b2f(m2.y) + h1) + lrelu(c1 * b2f(m3.y) + h1);
        a2 += lrelu(c2 * b2f(m0.z) + h2) + lrelu(c2 * b2f(m1.z) + h2)
            + lrelu(c2 * b2f(m2.z) + h2) + lrelu(c2 * b2f(m3.z) + h2);
        a3 += lrelu(c3 * b2f(m0.w) + h3) + lrelu(c3 * b2f(m1.w) + h3)
            + lrelu(c3 * b2f(m2.w) + h3) + lrelu(c3 * b2f(m3.w) + h3);
    }
    for (; e < e1; ++e) {
        int s0 = g_csr[e];
        ushort4 m0 = *(const ushort4*)(mb + s0 * 32 + g * 4);
        a0 += lrelu(c0 * b2f(m0.x) + h0);
        a1 += lrelu(c1 * b2f(m0.y) + h1);
        a2 += lrelu(c2 * b2f(m0.z) + h2);
        a3 += lrelu(c3 * b2f(m0.w) + h3);
    }
    *(float4*)(gA + OFF_AGG + n * 32 + g * 4) = make_float4(a0, a1, a2, a3);
}

// ---------------- update linear: PB = [h, agg] @ Wu + bu, stats ----------------
__global__ void k_upd_v17(int off_h, int off_out,
                          const float* __restrict__ Wu_i, const float* __restrict__ bu_i,
                          int st_out)
{
    int j = threadIdx.x & 31, ns = threadIdx.x >> 5;
    float wc[64];
    #pragma unroll
    for (int k = 0; k < 64; ++k) wc[k] = Wu_i[k * 32 + j];
    float bb = bu_i[j];
    __shared__ float sH[8][32];
    __shared__ float sA[8][32];
    __shared__ float red[64];
    if (threadIdx.x < 64) red[threadIdx.x] = 0.f;
    __syncthreads();
    float s1 = 0.f, s2 = 0.f;
    for (int t = blockIdx.x; t < NN / 8; t += gridDim.x) {
        int n = t * 8 + ns;
        sH[ns][j] = gA[off_h + n * 32 + j];
        sA[ns][j] = gA[OFF_AGG + n * 32 + j];
        __syncthreads();
        float acc = bb;
        #pragma unroll
        for (int k = 0; k < 32; k += 4) {
            float4 h4 = *(const float4*)&sH[ns][k];
            acc += h4.x * wc[k] + h4.y * wc[k + 1] + h4.z * wc[k + 2] + h4.w * wc[k + 3];
            float4 a4 = *(const float4*)&sA[ns][k];
            acc += a4.x * wc[32 + k] + a4.y * wc[32 + k + 1] + a4.z * wc[32 + k + 2] + a4.w * wc[32 + k + 3];
        }
        gA[off_out + n * 32 + j] = acc;
        s1 += acc; s2 += acc * acc;
        __syncthreads();
    }
    atomicAdd(&red[j], s1);
    atomicAdd(&red[j + 32], s2);
    __syncthreads();
    if (threadIdx.x < 64)
        atomicAdd(&gA[st_out + (blockIdx.x & (STC - 1)) * 64 + threadIdx.x], red[threadIdx.x]);
}

// ---------------- fused final MLP: 32 nodes/block, NO sW staging (52 KB LDS) ----------------
__global__ __launch_bounds__(256) void k_final_v17(
    int off_h,
    const float* __restrict__ Wf0, const float* __restrict__ bf0,
    const float* __restrict__ Wf1, const float* __restrict__ bf1,
    const float* __restrict__ Wf2, const float* __restrict__ bf2,
    const float* __restrict__ Wf3, const float* __restrict__ bf3,
    const float* __restrict__ Wo,  const float* __restrict__ bo,
    float* __restrict__ out)
{
    __shared__ float sH[32][32];
    __shared__ float sA[32][256];
    __shared__ float sB[32][128];
    float* sBf = &sB[0][0];
    int tid = threadIdx.x;
    int base = blockIdx.x * 32;
    const float* hin = gA + off_h;

    for (int idx = tid; idx < 1024; idx += 256)
        sH[idx >> 5][idx & 31] = hin[base * 32 + idx];
    __syncthreads();

    // L0: 32->256
    {
        float w0[32];
        #pragma unroll
        for (int k = 0; k < 32; ++k) w0[k] = Wf0[k * 256 + tid];
        float bb = bf0[tid];
        for (int n = 0; n < 32; ++n) {
            float acc = bb;
            #pragma unroll
            for (int k = 0; k < 32; k += 4) {
                float4 h4 = *(const float4*)&sH[n][k];
                acc += h4.x * w0[k] + h4.y * w0[k + 1] + h4.z * w0[k + 2] + h4.w * w0[k + 3];
            }
            sA[n][tid] = lrelu(acc);
        }
    }
    __syncthreads();

    // L1: 256->128
    {
        int j = tid & 63, ng = tid >> 6;
        float acc0[8], acc1[8];
        float bb0 = bf1[j], bb1 = bf1[j + 64];
        #pragma unroll
        for (int q = 0; q < 8; ++q) { acc0[q] = bb0; acc1[q] = bb1; }
        for (int r4 = 0; r4 < 256; r4 += 4) {
            float wa[4], wb[4];
            #pragma unroll
            for (int i = 0; i < 4; ++i) {
                wa[i] = Wf1[(r4 + i) * 128 + j];
                wb[i] = Wf1[(r4 + i) * 128 + j + 64];
            }
            #pragma unroll
            for (int q = 0; q < 8; ++q) {
                float4 a4 = *(const float4*)&sA[ng * 8 + q][r4];
                acc0[q] += a4.x * wa[0] + a4.y * wa[1] + a4.z * wa[2] + a4.w * wa[3];
                acc1[q] += a4.x * wb[0] + a4.y * wb[1] + a4.z * wb[2] + a4.w * wb[3];
            }
        }
        __syncthreads();
        #pragma unroll
        for (int q = 0; q < 8; ++q) {
            int n = ng * 8 + q;
            sB[n][j]      = lrelu(acc0[q]);
            sB[n][j + 64] = lrelu(acc1[q]);
        }
    }
    __syncthreads();

    // L2: 128->64
    {
        int j = tid & 63, ng = tid >> 6;
        float acc[8];
        float bb = bf2[j];
        #pragma unroll
        for (int q = 0; q < 8; ++q) acc[q] = bb;
        for (int r4 = 0; r4 < 128; r4 += 4) {
            float w4[4];
            #pragma unroll
            for (int i = 0; i < 4; ++i) w4[i] = Wf2[(r4 + i) * 64 + j];
            #pragma unroll
            for (int q = 0; q < 8; ++q) {
                float4 a4 = *(const float4*)&sB[ng * 8 + q][r4];
                acc[q] += a4.x * w4[0] + a4.y * w4[1] + a4.z * w4[2] + a4.w * w4[3];
            }
        }
        __syncthreads();
        #pragma unroll
        for (int q = 0; q < 8; ++q)
            sA[ng * 8 + q][j] = lrelu(acc[q]);
    }
    __syncthreads();

    // L3: 64->32
    {
        int j = tid & 31, ng = tid >> 5;
        float acc[4];
        float bb = bf3[j];
        #pragma unroll
        for (int q = 0; q < 4; ++q) acc[q] = bb;
        #pragma unroll
        for (int k4 = 0; k4 < 64; k4 += 4) {
            float w4[4];
            #pragma unroll
            for (int i = 0; i < 4; ++i) w4[i] = Wf3[(k4 + i) * 32 + j];
            #pragma unroll
            for (int q = 0; q < 4; ++q) {
                float4 a4 = *(const float4*)&sA[ng * 4 + q][k4];
                acc[q] += a4.x * w4[0] + a4.y * w4[1] + a4.z * w4[2] + a4.w * w4[3];
            }
        }
        __syncthreads();
        #pragma unroll
        for (int q = 0; q < 4; ++q)
            sBf[(ng * 4 + q) * 32 + j] = lrelu(acc[q]);
    }
    __syncthreads();

    // Out: 32->1 + sigmoid
    {
        int n = tid >> 3, p = tid & 7;
        const float* t3 = &sBf[n * 32];
        float s = 0.f;
        #pragma unroll
        for (int i = 0; i < 4; ++i) {
            int k = p * 4 + i;
            s += t3[k] * Wo[k];
        }
        s += __shfl_xor(s, 1);
        s += __shfl_xor(s, 2);
        s += __shfl_xor(s, 4);
        if (p == 0) {
            float z = s + bo[0];
            out[base + n] = 1.f / (1.f + __expf(-z));
        }
    }
}

extern "C" void kernel_launch(void* const* d_in, const int* in_sizes, int n_in,
                              void* d_out, int out_size, void* d_ws, size_t ws_size,
                              hipStream_t stream)
{
    (void)in_sizes; (void)n_in; (void)out_size; (void)d_ws; (void)ws_size;
    float* out = (float*)d_out;

    const float* x   = (const float*)d_in[0];
    const int*  col  = (const int*) d_in[1];
    const float* Wi0 = (const float*)d_in[2];
    const float* bi0 = (const float*)d_in[3];
    const float* gi0 = (const float*)d_in[4];
    const float* bei0= (const float*)d_in[5];
    const float* Wi1 = (const float*)d_in[6];
    const float* bi1 = (const float*)d_in[7];
    const float* gi1 = (const float*)d_in[8];
    const float* bei1= (const float*)d_in[9];
    const float* Wm  = (const float*)d_in[10];
    const float* bm  = (const float*)d_in[11];
    const float* gm  = (const float*)d_in[12];
    const float* bem = (const float*)d_in[13];
    const float* Wu  = (const float*)d_in[14];
    const float* bu  = (const float*)d_in[15];
    const float* gu  = (const float*)d_in[16];
    const float* beu = (const float*)d_in[17];
    const float* Wf0 = (const float*)d_in[18];
    const float* bf0 = (const float*)d_in[19];
    const float* Wf1 = (const float*)d_in[20];
    const float* bf1 = (const float*)d_in[21];
    const float* Wf2 = (const float*)d_in[22];
    const float* bf2 = (const float*)d_in[23];
    const float* Wf3 = (const float*)d_in[24];
    const float* bf3 = (const float*)d_in[25];
    const float* Wo  = (const float*)d_in[26];
    const float* bo  = (const float*)d_in[27];

    const int st_i0 = OFF_STATS;
    const int st_i1 = OFF_STATS + ST_STRIDE;
    const int st_m  = OFF_STATS + 2 * ST_STRIDE;    // + i*ST_STRIDE
    const int st_u  = OFF_STATS + 12 * ST_STRIDE;   // + i*ST_STRIDE

    const int RING[4] = { OFF_RING, OFF_RING + NV, OFF_RING + 2 * NV, OFF_RING + 3 * NV };

    dim3 blk(256);
    k_zero_v17<<<NBLK, blk, 0, stream>>>();
    k_count_v17<<<6250, blk, 0, stream>>>(col);
    k_bsum_v17<<<NBLK, blk, 0, stream>>>();
    k_bscan_v17<<<1, 512, 0, stream>>>();
    k_bexp_v17<<<NBLK, blk, 0, stream>>>();
    k_fill_v17<<<6250, blk, 0, stream>>>(col);

    // init MLP: x -> h0 (ring[0]); last k_nl chains layer-0 msg linear into bf16 MSGB
    k_init0_v17<<<1024, blk, 0, stream>>>(x, Wi0, bi0);
    k_nl_v17<<<1024, blk, 0, stream>>>(OFF_PA, OFF_PB, 0, st_i0, gi0, bei0, -1, -1, Wi1, bi1, st_i1);
    k_nl_v17<<<1024, blk, 0, stream>>>(OFF_PB, 0, 1, st_i1, gi1, bei1, -1, RING[0], Wm, bm, st_m);

    for (int i = 0; i < 10; ++i) {
        int h_cur = RING[i & 3];
        int h_new = RING[(i + 1) & 3];
        int resid = (i >= 2) ? RING[(i - 2) & 3] : -1;
        k_gather_v17<<<3125, blk, 0, stream>>>(st_m + i * ST_STRIDE, gm + i * 32, bem + i * 32);
        k_upd_v17<<<1024, blk, 0, stream>>>(h_cur, OFF_PB, Wu + i * 2048, bu + i * 32,
                                            st_u + i * ST_STRIDE);
        const float* Wn = (i < 9) ? (Wm + (i + 1) * 1024) : nullptr;
        const float* bn = (i < 9) ? (bm + (i + 1) * 32) : nullptr;
        int st_next = (i < 9) ? (st_m + (i + 1) * ST_STRIDE) : 0;
        k_nl_v17<<<1024, blk, 0, stream>>>(OFF_PB, 0, 1, st_u + i * ST_STRIDE,
                                           gu + i * 32, beu + i * 32,
                                           resid, h_new, Wn, bn, st_next);
    }

    k_final_v17<<<3125, blk, 0, stream>>>(RING[2], Wf0, bf0, Wf1, bf1, Wf2, bf2,
                                          Wf3, bf3, Wo, bo, out);
}